// Round 12
// baseline (303.477 us; speedup 1.0000x reference)
//
#include <hip/hip_runtime.h>

#define N_NODES 50000
#define N_EDGES 800000
#define D1 64
#define D2 32
#define N_CLASSES 6
#define N_GRAPHS 128
#define CAP 64       // per-node src bucket capacity == wave size; deg max ~45 << 64
#define GB 782       // ceil(50000/64)
#define NFB 3125     // N_EDGES/256 fill blocks

typedef unsigned short u16;
typedef unsigned int u32;
typedef __attribute__((ext_vector_type(8))) short bf16x8;
typedef __attribute__((ext_vector_type(4))) float f32x4;

__device__ __forceinline__ float bf2f(u16 b) {
    u32 u = ((u32)b) << 16;
    float f;
    __builtin_memcpy(&f, &u, 4);
    return f;
}
__device__ __forceinline__ u16 f2bf(float f) {
    u32 u;
    __builtin_memcpy(&u, &f, 4);
    u32 r = (u + 0x7fffu + ((u >> 16) & 1u)) >> 16;
    return (u16)r;
}
__device__ __forceinline__ void split8(const float* v, bf16x8& hi, bf16x8& lo) {
#pragma unroll
    for (int j = 0; j < 8; ++j) {
        u16 h = f2bf(v[j]);
        hi[j] = (short)h;
        lo[j] = (short)f2bf(v[j] - bf2f(h));
    }
}
__device__ __forceinline__ float sigmoidf_(float x) {
    return 1.0f / (1.0f + __expf(-x));
}
__device__ __forceinline__ float tanhf_(float x) {
    return 1.0f - 2.0f / (__expf(2.0f * x) + 1.0f);
}

// ===== fused: fill (blocks 0..3124) + B/bias pack + mm L0 (compute-bound backfill) =====
__global__ __launch_bounds__(256) void fused_head_kernel(
        const int* __restrict__ ei, int* __restrict__ deg, u16* __restrict__ srcidx,
        const float* __restrict__ x, const float* __restrict__ W,
        const float* __restrict__ wih, const float* __restrict__ whh,
        const float* __restrict__ bih, const float* __restrict__ bhh,
        short* __restrict__ Bh, short* __restrict__ Bl, float* __restrict__ bias4,
        u16* __restrict__ m16) {
    int b = blockIdx.x;
    int tid = threadIdx.x;
    if (b < NFB) {
        // ---- bucketed fill: one edge per thread (deg pre-zeroed via memset) ----
        int e = b * 256 + tid;
        int d = ei[N_EDGES + e];
        int s = ei[e];
        int p = atomicAdd(&deg[d], 1);
        if (p < CAP) srcidx[d * CAP + p] = (u16)s;
    } else if (b < NFB + 128) {
        // ---- pack GRU B in fragment order ----
        int idx = (b - NFB) * 256 + tid;
        int j = idx & 7;
        int lane = (idx >> 3) & 63;
        int nt = (idx >> 9) & 15;
        int kt = idx >> 13;
        int k = kt * 32 + (lane >> 4) * 8 + j;
        int n = nt * 16 + (lane & 15);
        int g = n >> 6, d = n & 63;
        float v;
        if (g == 0)      v = (k < 64) ? wih[d * 64 + k] : whh[d * 64 + (k - 64)];
        else if (g == 1) v = (k < 64) ? wih[(64 + d) * 64 + k] : whh[(64 + d) * 64 + (k - 64)];
        else if (g == 2) v = (k < 64) ? wih[(128 + d) * 64 + k] : 0.f;
        else             v = (k < 64) ? 0.f : whh[(128 + d) * 64 + (k - 64)];
        u16 hi = f2bf(v);
        Bh[idx] = (short)hi;
        Bl[idx] = (short)f2bf(v - bf2f(hi));
    } else if (b == NFB + 128) {
        int j = tid;
        if (j < 64) {
            bias4[j] = bih[j] + bhh[j];
            bias4[64 + j] = bih[64 + j] + bhh[64 + j];
            bias4[128 + j] = bih[128 + j];
            bias4[192 + j] = bhh[128 + j];
        }
    } else {
        // ---- mm L0: m = x @ W0, raw f32 W (16 KB, L1-resident), split in-register ----
        int lane = tid & 63;
        int wv = tid >> 6;
        int node0 = (b - NFB - 129) * 64 + wv * 16;
        if (node0 >= N_NODES) return;
        int c0 = lane & 15, qr = lane >> 4;
        f32x4 acc[4];
#pragma unroll
        for (int nt = 0; nt < 4; ++nt) acc[nt] = (f32x4){0.f, 0.f, 0.f, 0.f};
#pragma unroll
        for (int kt = 0; kt < 2; ++kt) {
            int aoff = (node0 + c0) * 64 + kt * 32 + qr * 8;
            float tmp[8];
#pragma unroll
            for (int j = 0; j < 8; ++j) tmp[j] = x[aoff + j];
            bf16x8 ah, al;
            split8(tmp, ah, al);
            int k0 = kt * 32 + qr * 8;
#pragma unroll
            for (int nt = 0; nt < 4; ++nt) {
                int n = nt * 16 + c0;
                float wt[8];
#pragma unroll
                for (int j = 0; j < 8; ++j) wt[j] = W[(k0 + j) * 64 + n];
                bf16x8 bh, bl;
                split8(wt, bh, bl);
                acc[nt] = __builtin_amdgcn_mfma_f32_16x16x32_bf16(ah, bh, acc[nt], 0, 0, 0);
                acc[nt] = __builtin_amdgcn_mfma_f32_16x16x32_bf16(ah, bl, acc[nt], 0, 0, 0);
                acc[nt] = __builtin_amdgcn_mfma_f32_16x16x32_bf16(al, bh, acc[nt], 0, 0, 0);
            }
        }
#pragma unroll
        for (int nt = 0; nt < 4; ++nt)
#pragma unroll
            for (int r = 0; r < 4; ++r)
                m16[(node0 + qr * 4 + r) * 64 + nt * 16 + c0] = f2bf(acc[nt][r]);
    }
}

// ===== agg: wave per node; half-wave dword gather (2 edges in flight, 4B/lane) =====
__global__ __launch_bounds__(256) void agg_kernel(const u16* __restrict__ m16,
                                                  const int* __restrict__ deg,
                                                  const u16* __restrict__ srcidx,
                                                  short* __restrict__ aghi,
                                                  short* __restrict__ aglo) {
    int lane = threadIdx.x & 63;
    int wv = threadIdx.x >> 6;
    int node = blockIdx.x * 4 + wv;  // grid exact: 50000/4
    int cnt = __builtin_amdgcn_readfirstlane(deg[node]);
    cnt = cnt < CAP ? cnt : CAP;
    int bv = (int)srcidx[node * CAP + lane];  // bucket, one coalesced 128B row
    int half = lane >> 5;                     // 0: even edges, 1: odd edges
    int l = lane & 31;                        // dword index: features 2l, 2l+1
    const u32* m32 = (const u32*)m16;
    float a0 = 0.f, a1 = 0.f;
    int k = half;
    for (; k + 6 < cnt; k += 8) {
        int s0 = __shfl(bv, k);
        int s1 = __shfl(bv, k + 2);
        int s2 = __shfl(bv, k + 4);
        int s3 = __shfl(bv, k + 6);
        u32 d0 = m32[s0 * 32 + l];
        u32 d1 = m32[s1 * 32 + l];
        u32 d2 = m32[s2 * 32 + l];
        u32 d3 = m32[s3 * 32 + l];
        a0 += bf2f((u16)d0) + bf2f((u16)d1) + bf2f((u16)d2) + bf2f((u16)d3);
        a1 += bf2f((u16)(d0 >> 16)) + bf2f((u16)(d1 >> 16)) +
              bf2f((u16)(d2 >> 16)) + bf2f((u16)(d3 >> 16));
    }
    for (; k < cnt; k += 2) {
        int s = __shfl(bv, k);
        u32 d = m32[s * 32 + l];
        a0 += bf2f((u16)d);
        a1 += bf2f((u16)(d >> 16));
    }
    a0 += __shfl_xor(a0, 32);
    a1 += __shfl_xor(a1, 32);
    if (half == 0) {
        u16 h0 = f2bf(a0), h1 = f2bf(a1);
        u16 g0 = f2bf(a0 - bf2f(h0)), g1 = f2bf(a1 - bf2f(h1));
        ((u32*)aghi)[node * 32 + l] = (u32)h0 | ((u32)h1 << 16);
        ((u32*)aglo)[node * 32 + l] = (u32)g0 | ((u32)g1 << 16);
    }
}

// ===== GRU GEMM + gates; B read DIRECT from global (L2-resident, r11 lesson:
//       LDS staging = 8-way bank conflicts + barriers + occupancy loss).
//       Optional fused next-layer mm via wave-local LDS transpose tile. =====
template <bool L0, bool DO_MM, bool LAST>
__global__ __launch_bounds__(256) void gru_mfma(const short* __restrict__ aghi,
                                                const short* __restrict__ aglo,
                                                short* hhi, short* hlo,
                                                const short* __restrict__ Bh,
                                                const short* __restrict__ Bl,
                                                const float* __restrict__ bias4,
                                                const float* __restrict__ hin,  // x (L0) or h f32
                                                float* __restrict__ hout,
                                                const float* __restrict__ Wnext,
                                                u16* __restrict__ m16) {
    __shared__ float tile[4][16 * 65];  // wave-local transpose tiles (16.6 KB)
    int tid = threadIdx.x;
    int lane = tid & 63;
    int wv = tid >> 6;
    int node0 = blockIdx.x * 64 + wv * 16;
    if (node0 >= N_NODES) return;  // no barriers in this kernel: wave-granular
    int c0 = lane & 15, qr = lane >> 4;

    f32x4 acc[16];
#pragma unroll
    for (int nt = 0; nt < 16; ++nt) acc[nt] = (f32x4){0.f, 0.f, 0.f, 0.f};

#pragma unroll
    for (int kt = 0; kt < 4; ++kt) {
        bf16x8 ah, al;
        int aoff = (node0 + c0) * 64 + (kt & 1) * 32 + qr * 8;
        if (kt < 2) {
            ah = *(const bf16x8*)(aghi + aoff);
            al = *(const bf16x8*)(aglo + aoff);
        } else if (L0) {  // h half = x, split in-register
            float tmp[8];
#pragma unroll
            for (int j = 0; j < 8; ++j) tmp[j] = hin[aoff + j];
            split8(tmp, ah, al);
        } else {
            ah = *(const bf16x8*)(hhi + aoff);
            al = *(const bf16x8*)(hlo + aoff);
        }
#pragma unroll
        for (int nt = 0; nt < 16; ++nt) {
            int boff = (kt * 16 + nt) * 512 + lane * 8;
            bf16x8 bh = *(const bf16x8*)(Bh + boff);
            bf16x8 bl = *(const bf16x8*)(Bl + boff);
            acc[nt] = __builtin_amdgcn_mfma_f32_16x16x32_bf16(ah, bh, acc[nt], 0, 0, 0);
            acc[nt] = __builtin_amdgcn_mfma_f32_16x16x32_bf16(ah, bl, acc[nt], 0, 0, 0);
            acc[nt] = __builtin_amdgcn_mfma_f32_16x16x32_bf16(al, bh, acc[nt], 0, 0, 0);
        }
    }

    float* myTile = tile[wv];

    // gates: cols j, 64+j, 128+j, 192+j live in n-tiles jt, jt+4, jt+8, jt+12
#pragma unroll
    for (int r = 0; r < 4; ++r) {
        int row = node0 + qr * 4 + r;
#pragma unroll
        for (int jt = 0; jt < 4; ++jt) {
            int j = jt * 16 + c0;
            float rr = sigmoidf_(acc[jt][r] + bias4[j]);
            float zz = sigmoidf_(acc[4 + jt][r] + bias4[64 + j]);
            float nn = tanhf_(acc[8 + jt][r] + bias4[128 + j] +
                              rr * (acc[12 + jt][r] + bias4[192 + j]));
            float ho = hin[row * 64 + j];
            float v = (1.f - zz) * nn + zz * ho;
            hout[row * 64 + j] = v;
            if (!LAST) {
                u16 hi = f2bf(v);
                hhi[row * 64 + j] = (short)hi;
                hlo[row * 64 + j] = (short)f2bf(v - bf2f(hi));
            }
            if (DO_MM) myTile[(qr * 4 + r) * 65 + j] = v;
        }
    }

    if (DO_MM) {
        // mm next layer: m16[row] = h[row] @ Wnext; A from wave-local tile
        f32x4 macc[4];
#pragma unroll
        for (int nt = 0; nt < 4; ++nt) macc[nt] = (f32x4){0.f, 0.f, 0.f, 0.f};
#pragma unroll
        for (int kt = 0; kt < 2; ++kt) {
            float tmp[8];
            int k0 = kt * 32 + qr * 8;
#pragma unroll
            for (int j = 0; j < 8; ++j) tmp[j] = myTile[c0 * 65 + k0 + j];
            bf16x8 ah, al;
            split8(tmp, ah, al);
#pragma unroll
            for (int nt = 0; nt < 4; ++nt) {
                int n = nt * 16 + c0;
                float wt[8];
#pragma unroll
                for (int j = 0; j < 8; ++j) wt[j] = Wnext[(k0 + j) * 64 + n];
                bf16x8 bh, bl;
                split8(wt, bh, bl);
                macc[nt] = __builtin_amdgcn_mfma_f32_16x16x32_bf16(ah, bh, macc[nt], 0, 0, 0);
                macc[nt] = __builtin_amdgcn_mfma_f32_16x16x32_bf16(ah, bl, macc[nt], 0, 0, 0);
                macc[nt] = __builtin_amdgcn_mfma_f32_16x16x32_bf16(al, bh, macc[nt], 0, 0, 0);
            }
        }
#pragma unroll
        for (int nt = 0; nt < 4; ++nt)
#pragma unroll
            for (int r = 0; r < 4; ++r)
                m16[(node0 + qr * 4 + r) * 64 + nt * 16 + c0] = f2bf(macc[nt][r]);
    }
}

// relu + segment-mean partial sums: 4 chunks per graph (512 blocks)
__global__ __launch_bounds__(256) void pool_kernel(const float* __restrict__ h,
                                                   const int* __restrict__ batch,
                                                   float* __restrict__ pooledp) {
    int g = blockIdx.x >> 2, c = blockIdx.x & 3;
    int tid = threadIdx.x, lane = tid & 63, wv = tid >> 6;
    int lo, hi;
    {
        int a = 0, b = N_NODES;
        while (a < b) { int mid = (a + b) >> 1; if (batch[mid] < g) a = mid + 1; else b = mid; }
        lo = a;
    }
    {
        int a = lo, b = N_NODES;
        while (a < b) { int mid = (a + b) >> 1; if (batch[mid] < g + 1) a = mid + 1; else b = mid; }
        hi = a;
    }
    int len = hi - lo;
    int start = lo + (len * c) / 4;
    int end = lo + (len * (c + 1)) / 4;
    float acc = 0.f;
    for (int n = start + wv; n < end; n += 4) acc += fmaxf(h[n * 64 + lane], 0.f);
    __shared__ float red[4][64];
    red[wv][lane] = acc;
    __syncthreads();
    if (wv == 0) {
        pooledp[(g * 4 + c) * 64 + lane] =
            red[0][lane] + red[1][lane] + red[2][lane] + red[3][lane];
    }
}

// head: sum partials, mean, fc1+relu, fc2, log_softmax
__global__ __launch_bounds__(64) void head_kernel(const float* __restrict__ pooledp,
                                                  const int* __restrict__ batch,
                                                  const float* __restrict__ fc1w,
                                                  const float* __restrict__ fc1b,
                                                  const float* __restrict__ fc2w,
                                                  const float* __restrict__ fc2b,
                                                  float* __restrict__ out) {
    int g = blockIdx.x;
    int lane = threadIdx.x;
    __shared__ float pv[64];
    __shared__ float s1[32];
    __shared__ float s2[6];
    int lo, hi;
    {
        int a = 0, b = N_NODES;
        while (a < b) { int mid = (a + b) >> 1; if (batch[mid] < g) a = mid + 1; else b = mid; }
        lo = a;
    }
    {
        int a = lo, b = N_NODES;
        while (a < b) { int mid = (a + b) >> 1; if (batch[mid] < g + 1) a = mid + 1; else b = mid; }
        hi = a;
    }
    float s = pooledp[(g * 4 + 0) * 64 + lane] + pooledp[(g * 4 + 1) * 64 + lane] +
              pooledp[(g * 4 + 2) * 64 + lane] + pooledp[(g * 4 + 3) * 64 + lane];
    pv[lane] = s / fmaxf((float)(hi - lo), 1.f);
    __syncthreads();
    if (lane < 32) {
        float acc = fc1b[lane];
#pragma unroll
        for (int j = 0; j < 64; ++j) acc = fmaf(pv[j], fc1w[lane * 64 + j], acc);
        s1[lane] = fmaxf(acc, 0.f);
    }
    __syncthreads();
    if (lane < 6) {
        float acc = fc2b[lane];
#pragma unroll
        for (int j = 0; j < 32; ++j) acc = fmaf(s1[j], fc2w[lane * 32 + j], acc);
        s2[lane] = acc;
    }
    __syncthreads();
    if (lane == 0) {
        float mx = s2[0];
#pragma unroll
        for (int c = 1; c < 6; ++c) mx = fmaxf(mx, s2[c]);
        float se = 0.f;
#pragma unroll
        for (int c = 0; c < 6; ++c) se += __expf(s2[c] - mx);
        float lse = mx + __logf(se);
#pragma unroll
        for (int c = 0; c < 6; ++c) out[g * 6 + c] = s2[c] - lse;
    }
}

extern "C" void kernel_launch(void* const* d_in, const int* in_sizes, int n_in,
                              void* d_out, int out_size, void* d_ws, size_t ws_size,
                              hipStream_t stream) {
    const float* x    = (const float*)d_in[0];
    const int* ei     = (const int*)d_in[1];
    const int* batch  = (const int*)d_in[2];
    const float* W    = (const float*)d_in[3];
    const float* wih  = (const float*)d_in[4];
    const float* whh  = (const float*)d_in[5];
    const float* bih  = (const float*)d_in[6];
    const float* bhh  = (const float*)d_in[7];
    const float* fc1w = (const float*)d_in[8];
    const float* fc1b = (const float*)d_in[9];
    const float* fc2w = (const float*)d_in[10];
    const float* fc2b = (const float*)d_in[11];
    float* out = (float*)d_out;

    // ---- workspace layout ----
    float* h       = (float*)d_ws;               // 3.2M f
    float* pooledp = h + N_NODES * D1;           // 4*128*64 f
    float* bias4   = pooledp + 4 * N_GRAPHS * D1;
    int* deg       = (int*)(bias4 + 256);        // N_NODES
    u16* srcidx    = (u16*)(deg + N_NODES);      // N_NODES*CAP u16 = 6.4 MB
    size_t soff = ((size_t)(srcidx + N_NODES * CAP) + 15) & ~(size_t)15;
    u16* m16    = (u16*)soff;                    // 3.2M u16
    short* hhi  = (short*)(m16 + N_NODES * D1);  // 3.2M
    short* hlo  = hhi + N_NODES * D1;
    short* aghi = hlo + N_NODES * D1;
    short* aglo = aghi + N_NODES * D1;
    short* Bh   = aglo + N_NODES * D1;           // 32768
    short* Bl   = Bh + 32768;

    hipMemsetAsync(deg, 0, N_NODES * sizeof(int), stream);
    fused_head_kernel<<<NFB + 129 + GB, 256, 0, stream>>>(
        ei, deg, srcidx, x, W, wih, whh, bih, bhh, Bh, Bl, bias4, m16);

    // layer 0: agg -> gru(+fused mm of layer 1)
    agg_kernel<<<N_NODES / 4, 256, 0, stream>>>(m16, deg, srcidx, aghi, aglo);
    gru_mfma<true, true, false><<<GB, 256, 0, stream>>>(
        aghi, aglo, hhi, hlo, Bh, Bl, bias4, x, h, W + 4096, m16);
    // layer 1: agg -> gru (last: no hhi/hlo, no mm)
    agg_kernel<<<N_NODES / 4, 256, 0, stream>>>(m16, deg, srcidx, aghi, aglo);
    gru_mfma<false, false, true><<<GB, 256, 0, stream>>>(
        aghi, aglo, hhi, hlo, Bh, Bl, bias4, h, h, nullptr, nullptr);

    pool_kernel<<<4 * N_GRAPHS, 256, 0, stream>>>(h, batch, pooledp);
    head_kernel<<<N_GRAPHS, 64, 0, stream>>>(pooledp, batch, fc1w, fc1b, fc2w, fc2b, out);
}